// Round 1
// baseline (170.695 us; speedup 1.0000x reference)
//
#include <hip/hip_runtime.h>

// Problem constants (match reference)
#define N_NODES 4096
#define N_EDGES 131072
#define D_FEAT  512
#define K_SEL   2048      // ceil(0.5 * 4096)
#define NCHUNK  256       // counting-sort chunks
#define CHUNKLEN 512      // edges per chunk (NCHUNK*CHUNKLEN == N_EDGES)
#define NWORDS  128       // 4096 bits / 32

// ---------------- zero fill ----------------
__global__ void zero_u32(unsigned* __restrict__ p, int n) {
    int i = blockIdx.x * blockDim.x + threadIdx.x;
    if (i < n) p[i] = 0u;
}

// ---------------- stage 1: per-chunk histograms of src ----------------
__global__ void hist_kernel(const int* __restrict__ src, unsigned* __restrict__ hist) {
    int c = blockIdx.x;            // chunk
    int t = threadIdx.x;           // edge within chunk
    int e = c * CHUNKLEN + t;
    int s = src[e];
    atomicAdd(&hist[(size_t)c * N_NODES + s], 1u);
}

// ---------------- stage 2: per-node exclusive scan across chunks + degree ----------------
__global__ void colscan_kernel(unsigned* __restrict__ hist, unsigned* __restrict__ degree) {
    int n = blockIdx.x * blockDim.x + threadIdx.x;
    if (n >= N_NODES) return;
    unsigned run = 0;
    for (int c = 0; c < NCHUNK; ++c) {
        unsigned v = hist[(size_t)c * N_NODES + n];
        hist[(size_t)c * N_NODES + n] = run;   // chunk base within this node's segment
        run += v;
    }
    degree[n] = run;
}

// ---------------- stage 3: exclusive prefix over node degrees ----------------
__global__ void nodestart_kernel(const unsigned* __restrict__ degree,
                                 unsigned* __restrict__ node_start) {
    __shared__ unsigned part[1024];
    int t = threadIdx.x;  // 1024 threads, each owns 4 nodes
    unsigned loc[4];
    unsigned s = 0;
    for (int i = 0; i < 4; ++i) { loc[i] = s; s += degree[t * 4 + i]; }
    part[t] = s;
    __syncthreads();
    for (int off = 1; off < 1024; off <<= 1) {
        unsigned v = (t >= off) ? part[t - off] : 0u;
        __syncthreads();
        part[t] += v;
        __syncthreads();
    }
    unsigned base = (t > 0) ? part[t - 1] : 0u;
    for (int i = 0; i < 4; ++i) node_start[t * 4 + i] = base + loc[i];
    if (t == 1023) node_start[N_NODES] = part[1023];
}

// ---------------- stage 4: stable scatter (counting sort by src, edge order preserved) ----------------
__global__ void scatter_kernel(const int* __restrict__ src, const int* __restrict__ dst,
                               const float* __restrict__ att,
                               const unsigned* __restrict__ hist,
                               const unsigned* __restrict__ node_start,
                               float* __restrict__ s_att, int* __restrict__ s_dst,
                               unsigned* __restrict__ B) {
    __shared__ int lsrc[CHUNKLEN];
    int c = blockIdx.x, t = threadIdx.x;
    int e = c * CHUNKLEN + t;
    int s = src[e];
    lsrc[t] = s;
    __syncthreads();
    int r = 0;
    for (int i = 0; i < t; ++i) r += (lsrc[i] == s);   // stable in-chunk rank
    unsigned pos = node_start[s] + hist[(size_t)c * N_NODES + s] + (unsigned)r;
    s_att[pos] = att[e];
    int d = dst[e];
    s_dst[pos] = d;
    atomicOr(&B[(size_t)s * NWORDS + (d >> 5)], 1u << (d & 31));  // out-neighbor bitset
}

// ---------------- stage 5: per-node sequential f32 sum in edge order -> score ----------------
__global__ void score_kernel(const unsigned* __restrict__ degree,
                             const unsigned* __restrict__ node_start,
                             const float* __restrict__ s_att,
                             const int* __restrict__ dir_p,
                             float* __restrict__ scores) {
    int n = blockIdx.x * blockDim.x + threadIdx.x;
    if (n >= N_NODES) return;
    unsigned st = node_start[n], d = degree[n];
    float sum = 0.0f;
    for (unsigned i = 0; i < d; ++i) sum += s_att[st + i];   // original edge order
    float score = 0.0f;
    if (d > 0) {
        float df = (float)d;
        float mean = sum / df;                // fl(att_sum / degree)
        score = ((float)dir_p[0] * mean) * df; // (direction * att_mean) * degree
    }
    scores[n] = score;
}

// ---------------- stage 6: exact stable descending rank -> perm, batch, perm-out ----------------
__global__ void rank_kernel(const float* __restrict__ scores,
                            unsigned* __restrict__ permw,
                            const int* __restrict__ batch,
                            float* __restrict__ out_batch,
                            float* __restrict__ out_perm) {
    __shared__ float sc[N_NODES];   // 16 KiB
    int t = threadIdx.x;
    for (int i = t; i < N_NODES; i += blockDim.x) sc[i] = scores[i];
    __syncthreads();
    int n = blockIdx.x * blockDim.x + t;
    float s = sc[n];
    int rank = 0;
    for (int m = 0; m < N_NODES; ++m) {
        float v = sc[m];
        rank += (v > s) || (v == s && m < n);   // lax.top_k stability: lower index first
    }
    if (rank < K_SEL) {
        permw[rank] = (unsigned)n;
        out_perm[rank] = (float)n;
        out_batch[rank] = (float)batch[n];
    }
}

// ---------------- stage 7: x gather ----------------
__global__ void gather_x_kernel(const float* __restrict__ x,
                                const unsigned* __restrict__ permw,
                                float* __restrict__ out_x) {
    int p = blockIdx.x;
    int t = threadIdx.x;   // 128 threads, float4 each -> 512 floats
    unsigned n = permw[p];
    const float4* xs = (const float4*)(x + (size_t)n * D_FEAT);
    float4* od = (float4*)(out_x + (size_t)p * D_FEAT);
    od[t] = xs[t];
}

// ---------------- stage 8: 2-hop boolean adjacency among selected nodes ----------------
__global__ void adj_kernel(const unsigned* __restrict__ permw,
                           const unsigned* __restrict__ node_start,
                           const unsigned* __restrict__ degree,
                           const int* __restrict__ s_dst,
                           const unsigned* __restrict__ B,
                           float* __restrict__ out_adj) {
    __shared__ unsigned row[NWORDS];
    __shared__ unsigned pcol[K_SEL];   // 8 KiB
    int p = blockIdx.x;
    int t = threadIdx.x;   // 128
    unsigned n = permw[p];
    for (int i = t; i < K_SEL; i += 128) pcol[i] = permw[i];
    unsigned st = node_start[n], d = degree[n];
    unsigned acc = 0;
    for (unsigned i = 0; i < d; ++i) {
        int m = s_dst[st + i];                 // broadcast load
        acc |= B[(size_t)m * NWORDS + t];      // coalesced across t
    }
    row[t] = acc;
    __syncthreads();
    float* o = out_adj + (size_t)p * K_SEL;
    for (int q = t; q < K_SEL; q += 128) {
        unsigned pq = pcol[q];
        o[q] = (float)((row[pq >> 5] >> (pq & 31)) & 1u);
    }
}

extern "C" void kernel_launch(void* const* d_in, const int* in_sizes, int n_in,
                              void* d_out, int out_size, void* d_ws, size_t ws_size,
                              hipStream_t stream) {
    const float* x        = (const float*)d_in[0];
    const int*   eidx     = (const int*)d_in[1];
    const float* att      = (const float*)d_in[2];
    const int*   batch    = (const int*)d_in[3];
    const int*   dir_p    = (const int*)d_in[4];
    const int* src = eidx;
    const int* dst = eidx + N_EDGES;

    // workspace layout (bytes)
    char* ws = (char*)d_ws;
    unsigned* hist       = (unsigned*)(ws + 0);                       // 256*4096*4 = 4 MiB
    unsigned* degree     = (unsigned*)(ws + 4194304);                 // 16 KiB
    unsigned* node_start = (unsigned*)(ws + 4210688);                 // 16.4 KiB
    unsigned* permw      = (unsigned*)(ws + 4227584);                 // 8 KiB
    float*    scores     = (float*)   (ws + 4235776);                 // 16 KiB
    float*    s_att      = (float*)   (ws + 4252160);                 // 512 KiB
    int*      s_dst      = (int*)     (ws + 4776448);                 // 512 KiB
    unsigned* B          = (unsigned*)(ws + 5300736);                 // 2 MiB  (end ~7.1 MiB)

    // output layout (floats)
    float* out_x     = (float*)d_out;                          // 2048*512
    float* out_adj   = out_x + (size_t)K_SEL * D_FEAT;         // 2048*2048
    float* out_batch = out_adj + (size_t)K_SEL * K_SEL;        // 2048
    float* out_perm  = out_batch + K_SEL;                      // 2048

    // zero hist (1,048,576 u32) and B (524,288 u32)
    zero_u32<<<4096, 256, 0, stream>>>(hist, NCHUNK * N_NODES);
    zero_u32<<<2048, 256, 0, stream>>>(B, N_NODES * NWORDS);

    hist_kernel<<<NCHUNK, CHUNKLEN, 0, stream>>>(src, hist);
    colscan_kernel<<<N_NODES / 256, 256, 0, stream>>>(hist, degree);
    nodestart_kernel<<<1, 1024, 0, stream>>>(degree, node_start);
    scatter_kernel<<<NCHUNK, CHUNKLEN, 0, stream>>>(src, dst, att, hist, node_start,
                                                    s_att, s_dst, B);
    score_kernel<<<N_NODES / 256, 256, 0, stream>>>(degree, node_start, s_att, dir_p, scores);
    rank_kernel<<<N_NODES / 256, 256, 0, stream>>>(scores, permw, batch, out_batch, out_perm);
    gather_x_kernel<<<K_SEL, 128, 0, stream>>>(x, permw, out_x);
    adj_kernel<<<K_SEL, 128, 0, stream>>>(permw, node_start, degree, s_dst, B, out_adj);
}

// Round 2
// 56.344 us; speedup vs baseline: 3.0295x; 3.0295x over previous
//
#include <hip/hip_runtime.h>

// Problem constants (match reference)
#define N_NODES 4096
#define N_EDGES 131072
#define D_FEAT  512
#define K_SEL   2048      // ceil(0.5 * 4096)
#define NCHUNK  256       // counting-sort chunks
#define CHUNKLEN 512      // edges per chunk (NCHUNK*CHUNKLEN == N_EDGES)
#define NWORDS  128       // 4096 bits / 32

// ---------------- zero fill (B bitsets only; hist is fully written by hist_kernel) ----------------
__global__ void zero_u32(unsigned* __restrict__ p, int n) {
    int i = blockIdx.x * blockDim.x + threadIdx.x;
    if (i < n) p[i] = 0u;
}

// ---------------- stage 1: per-chunk histograms of src (LDS histogram, full write-out) ----------------
__global__ void hist_kernel(const int* __restrict__ src, unsigned* __restrict__ hist) {
    __shared__ unsigned h[N_NODES];   // 16 KiB
    int c = blockIdx.x;               // chunk
    int t = threadIdx.x;              // 512
    for (int i = t; i < N_NODES; i += CHUNKLEN) h[i] = 0u;
    __syncthreads();
    int s = src[c * CHUNKLEN + t];
    atomicAdd(&h[s], 1u);
    __syncthreads();
    uint4* d4 = (uint4*)(hist + (size_t)c * N_NODES);
    const uint4* h4 = (const uint4*)h;
    for (int i = t; i < N_NODES / 4; i += CHUNKLEN) d4[i] = h4[i];
}

// ---------------- stage 2: per-node exclusive scan across chunks + degree ----------------
__global__ void colscan_kernel(unsigned* __restrict__ hist, unsigned* __restrict__ degree) {
    int n = blockIdx.x * 64 + threadIdx.x;   // 64 blocks x 64
    unsigned run = 0;
    for (int c = 0; c < NCHUNK; ++c) {
        unsigned v = hist[(size_t)c * N_NODES + n];
        hist[(size_t)c * N_NODES + n] = run;   // chunk base within this node's segment
        run += v;
    }
    degree[n] = run;
}

// ---------------- stage 3: exclusive prefix over node degrees ----------------
__global__ void nodestart_kernel(const unsigned* __restrict__ degree,
                                 unsigned* __restrict__ node_start) {
    __shared__ unsigned part[1024];
    int t = threadIdx.x;  // 1024 threads, each owns 4 nodes
    unsigned loc[4];
    unsigned s = 0;
    for (int i = 0; i < 4; ++i) { loc[i] = s; s += degree[t * 4 + i]; }
    part[t] = s;
    __syncthreads();
    for (int off = 1; off < 1024; off <<= 1) {
        unsigned v = (t >= off) ? part[t - off] : 0u;
        __syncthreads();
        part[t] += v;
        __syncthreads();
    }
    unsigned base = (t > 0) ? part[t - 1] : 0u;
    for (int i = 0; i < 4; ++i) node_start[t * 4 + i] = base + loc[i];
    if (t == 1023) node_start[N_NODES] = part[1023];
}

// ---------------- stage 4: stable scatter (counting sort by src, edge order preserved) ----------------
__global__ void scatter_kernel(const int* __restrict__ src, const int* __restrict__ dst,
                               const float* __restrict__ att,
                               const unsigned* __restrict__ hist,
                               const unsigned* __restrict__ node_start,
                               float* __restrict__ s_att, int* __restrict__ s_dst,
                               unsigned* __restrict__ B) {
    __shared__ int lsrc[CHUNKLEN];
    int c = blockIdx.x, t = threadIdx.x;
    int e = c * CHUNKLEN + t;
    int s = src[e];
    lsrc[t] = s;
    __syncthreads();
    int r = 0;
    for (int i = 0; i < t; ++i) r += (lsrc[i] == s);   // stable in-chunk rank
    unsigned pos = node_start[s] + hist[(size_t)c * N_NODES + s] + (unsigned)r;
    s_att[pos] = att[e];
    int d = dst[e];
    s_dst[pos] = d;
    atomicOr(&B[(size_t)s * NWORDS + (d >> 5)], 1u << (d & 31));  // out-neighbor bitset
}

// ---------------- stage 5: per-node sequential f32 sum in edge order -> score ----------------
__global__ void score_kernel(const unsigned* __restrict__ degree,
                             const unsigned* __restrict__ node_start,
                             const float* __restrict__ s_att,
                             const int* __restrict__ dir_p,
                             float* __restrict__ scores) {
    int n = blockIdx.x * 64 + threadIdx.x;   // 64 blocks x 64
    unsigned st = node_start[n], d = degree[n];
    float sum = 0.0f;
    for (unsigned i = 0; i < d; ++i) sum += s_att[st + i];   // original edge order
    float score = 0.0f;
    if (d > 0) {
        float df = (float)d;
        float mean = sum / df;                 // fl(att_sum / degree)
        score = ((float)dir_p[0] * mean) * df; // (direction * att_mean) * degree
    }
    scores[n] = score;
}

// ---------------- stage 6: exact stable descending rank; one WAVE per node ----------------
__global__ void rank_kernel(const float* __restrict__ scores,
                            unsigned* __restrict__ permw,
                            const int* __restrict__ batch,
                            float* __restrict__ out_batch,
                            float* __restrict__ out_perm) {
    int t = threadIdx.x;
    int wave = t >> 6, lane = t & 63;
    int n = (blockIdx.x << 2) + wave;        // 1024 blocks x 4 waves
    float s = scores[n];
    const float4* sc4 = (const float4*)scores;
    int r = 0;
    #pragma unroll
    for (int i = 0; i < 16; ++i) {
        int q = lane + (i << 6);             // float4 index, coalesced
        float4 v = sc4[q];
        int m = q << 2;
        r += (v.x > s) || (v.x == s && (m + 0) < n);
        r += (v.y > s) || (v.y == s && (m + 1) < n);
        r += (v.z > s) || (v.z == s && (m + 2) < n);
        r += (v.w > s) || (v.w == s && (m + 3) < n);
    }
    #pragma unroll
    for (int off = 32; off; off >>= 1) r += __shfl_down(r, off);
    if (lane == 0 && r < K_SEL) {
        permw[r] = (unsigned)n;
        out_perm[r] = (float)n;
        out_batch[r] = (float)batch[n];
    }
}

// ---------------- stage 7: x gather + 2-hop boolean adjacency (fused, one block per selected node) ----------------
__global__ void adj_kernel(const float* __restrict__ x,
                           const unsigned* __restrict__ permw,
                           const unsigned* __restrict__ node_start,
                           const unsigned* __restrict__ degree,
                           const int* __restrict__ s_dst,
                           const unsigned* __restrict__ B,
                           float* __restrict__ out_x,
                           float* __restrict__ out_adj) {
    __shared__ int ldst[128];
    __shared__ unsigned row[NWORDS];
    int p = blockIdx.x;
    int t = threadIdx.x;   // 128
    unsigned n = permw[p];

    // x gather: 512 floats as 128 float4
    const float4* xs = (const float4*)(x + (size_t)n * D_FEAT);
    float4* od = (float4*)(out_x + (size_t)p * D_FEAT);
    od[t] = xs[t];

    unsigned st = node_start[n], d = degree[n];
    unsigned acc = 0;
    for (unsigned base = 0; base < d; base += 128) {
        unsigned cnt = min(128u, d - base);
        __syncthreads();
        if (t < (int)cnt) ldst[t] = s_dst[st + base + t];   // stage neighbor ids
        __syncthreads();
        for (unsigned i = 0; i < cnt; ++i)
            acc |= B[(size_t)ldst[i] * NWORDS + t];         // coalesced 512B rows, pipelined
    }
    row[t] = acc;
    __syncthreads();
    float* o = out_adj + (size_t)p * K_SEL;
    for (int q = t; q < K_SEL; q += 128) {
        unsigned pq = permw[q];   // L1-resident, coalesced
        o[q] = (float)((row[pq >> 5] >> (pq & 31)) & 1u);
    }
}

extern "C" void kernel_launch(void* const* d_in, const int* in_sizes, int n_in,
                              void* d_out, int out_size, void* d_ws, size_t ws_size,
                              hipStream_t stream) {
    const float* x        = (const float*)d_in[0];
    const int*   eidx     = (const int*)d_in[1];
    const float* att      = (const float*)d_in[2];
    const int*   batch    = (const int*)d_in[3];
    const int*   dir_p    = (const int*)d_in[4];
    const int* src = eidx;
    const int* dst = eidx + N_EDGES;

    // workspace layout (bytes)
    char* ws = (char*)d_ws;
    unsigned* hist       = (unsigned*)(ws + 0);                       // 256*4096*4 = 4 MiB
    unsigned* degree     = (unsigned*)(ws + 4194304);                 // 16 KiB
    unsigned* node_start = (unsigned*)(ws + 4210688);                 // 16.4 KiB
    unsigned* permw      = (unsigned*)(ws + 4227584);                 // 8 KiB
    float*    scores     = (float*)   (ws + 4235776);                 // 16 KiB
    float*    s_att      = (float*)   (ws + 4252160);                 // 512 KiB
    int*      s_dst      = (int*)     (ws + 4776448);                 // 512 KiB
    unsigned* B          = (unsigned*)(ws + 5300736);                 // 2 MiB  (end ~7.1 MiB)

    // output layout (floats)
    float* out_x     = (float*)d_out;                          // 2048*512
    float* out_adj   = out_x + (size_t)K_SEL * D_FEAT;         // 2048*2048
    float* out_batch = out_adj + (size_t)K_SEL * K_SEL;        // 2048
    float* out_perm  = out_batch + K_SEL;                      // 2048

    // zero B (524,288 u32); hist is fully overwritten by hist_kernel
    zero_u32<<<2048, 256, 0, stream>>>(B, N_NODES * NWORDS);

    hist_kernel<<<NCHUNK, CHUNKLEN, 0, stream>>>(src, hist);
    colscan_kernel<<<64, 64, 0, stream>>>(hist, degree);
    nodestart_kernel<<<1, 1024, 0, stream>>>(degree, node_start);
    scatter_kernel<<<NCHUNK, CHUNKLEN, 0, stream>>>(src, dst, att, hist, node_start,
                                                    s_att, s_dst, B);
    score_kernel<<<64, 64, 0, stream>>>(degree, node_start, s_att, dir_p, scores);
    rank_kernel<<<1024, 256, 0, stream>>>(scores, permw, batch, out_batch, out_perm);
    adj_kernel<<<K_SEL, 128, 0, stream>>>(x, permw, node_start, degree, s_dst, B,
                                          out_x, out_adj);
}

// Round 3
// 47.144 us; speedup vs baseline: 3.6208x; 1.1952x over previous
//
#include <hip/hip_runtime.h>

// Problem constants (match reference)
#define N_NODES 4096
#define N_EDGES 131072
#define D_FEAT  512
#define K_SEL   2048      // ceil(0.5 * 4096)
#define MAXDEG  128       // slot capacity per node (mean deg 32, max ~55; 128 is ~11 sigma)
#define NWORDS  128       // 4096 bits / 32

// ---------------- stage 0: zero B bitset + cnt (contiguous range) ----------------
__global__ void zero_kernel(unsigned* __restrict__ p, int n) {
    int i = blockIdx.x * 256 + threadIdx.x;
    if (i < n) p[i] = 0u;
}

// ---------------- stage 1: build per-node slot lists (unordered) + degree + out-neighbor bitset ----
// slots[s][pos] = (eidx << 12) | dst  — eidx fits 17 bits, dst fits 12 bits.
// atomicAdd order is nondeterministic but all consumers are order-independent
// (score re-sorts by eidx; B/adj are ORs) -> outputs deterministic.
__global__ void build_kernel(const int* __restrict__ src, const int* __restrict__ dst,
                             unsigned* __restrict__ cnt, unsigned* __restrict__ slots,
                             unsigned* __restrict__ B) {
    int e = blockIdx.x * 512 + threadIdx.x;
    int s = src[e];
    int d = dst[e];
    unsigned pos = atomicAdd(&cnt[s], 1u);
    if (pos < MAXDEG) slots[((unsigned)s << 7) + pos] = ((unsigned)e << 12) | (unsigned)d;
    atomicOr(&B[((size_t)s << 7) + (unsigned)(d >> 5)], 1u << (d & 31));
}

// ---------------- stage 2: score; ONE WAVE per node, exact edge-order fp32 sum ----------------
__global__ void score_kernel(const unsigned* __restrict__ cnt,
                             const unsigned* __restrict__ slots,
                             const float* __restrict__ att,
                             const int* __restrict__ dir_p,
                             float* __restrict__ scores) {
    __shared__ float a_ord[4][MAXDEG];   // 2 KiB
    int t = threadIdx.x, wave = t >> 6, lane = t & 63;
    int n = blockIdx.x * 4 + wave;       // 1024 blocks x 4 waves = 4096 nodes
    unsigned nb = (unsigned)n << 7;
    unsigned d = min(cnt[n], (unsigned)MAXDEG);
    // load up to 2 packed keys per lane; invalid -> UINT_MAX (sorts last, never counted)
    unsigned v0 = (lane < (int)d)        ? slots[nb + lane]      : 0xFFFFFFFFu;
    unsigned v1 = ((lane + 64) < (int)d) ? slots[nb + lane + 64] : 0xFFFFFFFFu;
    int r0 = 0, r1 = 0;
    int dk = (d < 64u) ? (int)d : 64;    // wave-uniform loop bound
    if (d <= 64u) {
        for (int k = 0; k < dk; ++k) {
            unsigned a = __shfl(v0, k);
            r0 += (a < v0);
        }
    } else {
        for (int k = 0; k < dk; ++k) {
            unsigned a = __shfl(v0, k);
            unsigned b = __shfl(v1, k);
            r0 += (a < v0) + (b < v0);
            r1 += (a < v1) + (b < v1);
        }
    }
    // scatter att into edge order (rank by packed key == rank by eidx)
    if (lane < (int)d)        a_ord[wave][r0] = att[v0 >> 12];
    if ((lane + 64) < (int)d) a_ord[wave][r1] = att[v1 >> 12];
    __syncthreads();
    if (lane == 0) {
        float sum = 0.0f;
        for (unsigned i = 0; i < d; ++i) sum += a_ord[wave][i];   // sequential, edge order
        float score = 0.0f;
        if (d > 0) {
            float df = (float)d;
            float mean = sum / df;                  // fl(att_sum / degree)
            score = ((float)dir_p[0] * mean) * df;  // (direction * att_mean) * degree
        }
        scores[n] = score;
    }
}

// ---------------- stage 3: exact stable descending rank + fused x gather ----------------
__global__ void rank_kernel(const float* __restrict__ scores,
                            const int* __restrict__ batch,
                            const float* __restrict__ x,
                            unsigned* __restrict__ permw,
                            float* __restrict__ out_x,
                            float* __restrict__ out_batch,
                            float* __restrict__ out_perm) {
    int t = threadIdx.x, wave = t >> 6, lane = t & 63;
    int n = blockIdx.x * 4 + wave;       // 1024 blocks x 4 waves
    float s = scores[n];
    const float4* sc4 = (const float4*)scores;
    int r = 0;
    #pragma unroll
    for (int i = 0; i < 16; ++i) {
        int q = lane + (i << 6);         // float4 index, coalesced, L1-resident
        float4 v = sc4[q];
        int m = q << 2;
        r += (v.x > s) || (v.x == s && (m + 0) < n);
        r += (v.y > s) || (v.y == s && (m + 1) < n);
        r += (v.z > s) || (v.z == s && (m + 2) < n);
        r += (v.w > s) || (v.w == s && (m + 3) < n);
    }
    #pragma unroll
    for (int off = 32; off; off >>= 1) r += __shfl_down(r, off);
    r = __shfl(r, 0);                    // broadcast rank to all lanes
    if (r < K_SEL) {
        if (lane == 0) {
            permw[r] = (unsigned)n;
            out_perm[r] = (float)n;
            out_batch[r] = (float)batch[n];
        }
        // whole wave copies the selected x row: 512 floats = 128 float4
        const float4* xs = (const float4*)(x + (size_t)n * D_FEAT);
        float4* od = (float4*)(out_x + (size_t)r * D_FEAT);
        od[lane] = xs[lane];
        od[lane + 64] = xs[lane + 64];
    }
}

// ---------------- stage 4: 2-hop boolean adjacency among selected nodes ----------------
__global__ void adj_kernel(const unsigned* __restrict__ permw,
                           const unsigned* __restrict__ cnt,
                           const unsigned* __restrict__ slots,
                           const unsigned* __restrict__ B,
                           float* __restrict__ out_adj) {
    __shared__ unsigned nbr[MAXDEG];
    __shared__ unsigned rowH[2][NWORDS];
    int p = blockIdx.x, t = threadIdx.x;   // 256 threads
    unsigned n = permw[p];
    unsigned d = min(cnt[n], (unsigned)MAXDEG);
    if (t < (int)d) nbr[t] = slots[((size_t)n << 7) + t] & 0xFFFu;
    __syncthreads();
    int w = t & 127, h = t >> 7;
    unsigned acc = 0;
    for (unsigned i = (unsigned)h; i < d; i += 2)
        acc |= B[((size_t)nbr[i] << 7) + w];   // 512B coalesced rows, L2-resident
    rowH[h][w] = acc;
    __syncthreads();
    if (t < NWORDS) rowH[0][t] |= rowH[1][t];
    __syncthreads();
    float4* o4 = (float4*)(out_adj + (size_t)p * K_SEL);
    #pragma unroll
    for (int i = 0; i < 2; ++i) {
        int q4 = t + (i << 8);             // 512 float4 per row
        int q = q4 << 2;
        unsigned c0 = permw[q], c1 = permw[q + 1], c2 = permw[q + 2], c3 = permw[q + 3];
        float4 v;
        v.x = (float)((rowH[0][c0 >> 5] >> (c0 & 31)) & 1u);
        v.y = (float)((rowH[0][c1 >> 5] >> (c1 & 31)) & 1u);
        v.z = (float)((rowH[0][c2 >> 5] >> (c2 & 31)) & 1u);
        v.w = (float)((rowH[0][c3 >> 5] >> (c3 & 31)) & 1u);
        o4[q4] = v;
    }
}

extern "C" void kernel_launch(void* const* d_in, const int* in_sizes, int n_in,
                              void* d_out, int out_size, void* d_ws, size_t ws_size,
                              hipStream_t stream) {
    const float* x     = (const float*)d_in[0];
    const int*   eidx  = (const int*)d_in[1];
    const float* att   = (const float*)d_in[2];
    const int*   batch = (const int*)d_in[3];
    const int*   dir_p = (const int*)d_in[4];
    const int* src = eidx;
    const int* dst = eidx + N_EDGES;

    // workspace layout (bytes); B and cnt contiguous so one zero pass covers both
    char* ws = (char*)d_ws;
    unsigned* B      = (unsigned*)(ws + 0);        // 4096*128*4 = 2,097,152
    unsigned* cnt    = (unsigned*)(ws + 2097152);  // 16,384
    float*    scores = (float*)   (ws + 2113536);  // 16,384
    unsigned* permw  = (unsigned*)(ws + 2129920);  // 8,192
    unsigned* slots  = (unsigned*)(ws + 2138112);  // 2,097,152 (end ~4.24 MB)

    // output layout (floats)
    float* out_x     = (float*)d_out;                          // 2048*512
    float* out_adj   = out_x + (size_t)K_SEL * D_FEAT;         // 2048*2048
    float* out_batch = out_adj + (size_t)K_SEL * K_SEL;        // 2048
    float* out_perm  = out_batch + K_SEL;                      // 2048

    const int nzero = (N_NODES * NWORDS) + N_NODES;            // B + cnt = 528,384 u32
    zero_kernel<<<(nzero + 255) / 256, 256, 0, stream>>>(B, nzero);
    build_kernel<<<N_EDGES / 512, 512, 0, stream>>>(src, dst, cnt, slots, B);
    score_kernel<<<N_NODES / 4, 256, 0, stream>>>(cnt, slots, att, dir_p, scores);
    rank_kernel<<<N_NODES / 4, 256, 0, stream>>>(scores, batch, x, permw,
                                                 out_x, out_batch, out_perm);
    adj_kernel<<<K_SEL, 256, 0, stream>>>(permw, cnt, slots, B, out_adj);
}